// Round 12
// baseline (49.475 us; speedup 1.0000x reference)
//
#include <hip/hip_runtime.h>

typedef _Float16 half8 __attribute__((ext_vector_type(8)));
typedef _Float16 half4 __attribute__((ext_vector_type(4)));
typedef float f32x4 __attribute__((ext_vector_type(4)));

#define W 512
#define H 512
#define NPIX (16.0f*3.0f*512.0f*512.0f)
#define NACC 64
#define SROWS 78           // staged rows (TP idx 0..76 needed; 77 valid + slack)
#define SSTR 52            // stage row stride in halves (104 B: 26-bank spread)
#define AH 4056            // halves per staged array = SROWS*SSTR
#define ARRB 8112          // bytes per staged array
#define TPSTR 80           // TP rowidx capacity per outcol (halves)
#define TPL 2560           // halves per TP plane = 32*TPSTR
#define NT 8               // tiles per persistent block (6144 / 768)

#define LGKM0()  asm volatile("s_waitcnt lgkmcnt(0)" ::: "memory")
#define VMCNT0() asm volatile("s_waitcnt vmcnt(0)" ::: "memory")
#define BAR()    { asm volatile("" ::: "memory"); __builtin_amdgcn_s_barrier(); asm volatile("" ::: "memory"); }
#define MFMA(A,B) __builtin_amdgcn_mfma_f32_16x16x32_f16((A),(B),zero4,0,0,0)

// Block = 64 out rows x 32 out cols, 256 threads (4 waves), 3 blocks/CU.
// Grid = 768 persistent blocks x NT=8 tiles. 48 planes x 8 ty x 16 tx = 6144 tiles.
__global__ __launch_bounds__(256) void ssim_main(const float* __restrict__ pred,
                                                 const float* __restrict__ targ,
                                                 const float* __restrict__ win,
                                                 float* __restrict__ acc) {
    const int tid  = threadIdx.x;
    const int lane = tid & 63;
    const int wv   = tid >> 6;          // wave 0..3
    const int lo   = lane & 15;
    const int hi   = lane >> 4;

    __shared__ _Float16 stageA[2 * AH];   // 16224 B: pred(0..AH) + targ(AH..)
    __shared__ _Float16 stageB[2 * AH];   // 16224 B
    __shared__ _Float16 TP[4 * TPL];      // 20480 B: 0:mu1 1:mu2 2:q 3:pt
    __shared__ _Float16 gw[64];
    __shared__ float wsum[4];

    // gw[18+d] = g[d] for d in [0,10], zero elsewhere (g from window row 5).
    if (tid < 64) {
        const int d = tid - 18;
        float val = 0.f;
        if (d >= 0 && d <= 10)
            val = win[55 + d] * __builtin_amdgcn_rcpf(sqrtf(win[60]));
        gw[tid] = (_Float16)val;
    }
    // Zero TP once (guarantees idx 77..79 stay 0 forever: masked H-store).
    {
        const half4 z4 = {(_Float16)0.f, (_Float16)0.f, (_Float16)0.f, (_Float16)0.f};
        #pragma unroll
        for (int i = 0; i < 10; ++i)
            *(half4*)&TP[4 * (i * 256 + tid)] = z4;
    }
    __syncthreads();

    // Band matrix (both passes): B[n][k] = g[k - n - 3]  (validated R6-R11).
    half8 Bw;
    #pragma unroll
    for (int j = 0; j < 8; ++j)
        Bw[j] = gw[15 + hi * 8 + j - lo];

    // Per-slot stage constants. Chunk id = s*256+tid in [0,1872):
    // arr = id>=936; cid = id - 936*arr; r = cid/12; cc = cid%12.
    // Stage origin (y0-8, x0-8); chunk covers 4 cols at gx = x0-8+4cc.
    int pr[8], pc[8], wo[8];
    #pragma unroll
    for (int s = 0; s < 8; ++s) {
        const int id  = s * 256 + tid;
        const bool ok = id < 1872;
        const int arr = (id >= 936) ? 1 : 0;
        const int cid = id - 936 * arr;
        const int r   = (cid * 5462) >> 16;      // exact /12 for cid < 1200
        const int cc  = cid - r * 12;
        pr[s] = ok ? r : (1 << 20);
        pc[s] = cc * 4 - 8;
        wo[s] = ok ? (arr * ARRB + r * 104 + cc * 8) : -1;
    }

    const f32x4 zero4 = {0.f, 0.f, 0.f, 0.f};
    const float C1 = 1e-4f, C2 = 9e-4f;
    f32x4 pre[8];
    float sum = 0.f;

    // XCD swizzle (768 = 8*96, bijective); 8 consecutive x-tiles per block.
    const int bsw = (blockIdx.x & 7) * 96 + (blockIdx.x >> 3);
    const int t0  = bsw * NT;

#define LOADREGS(tidx)                                                       \
    {                                                                        \
        const int nc = (tidx) >> 7, rem = (tidx) & 127;                      \
        const int y0 = (rem >> 4) * 64, x0 = (rem & 15) * 32;                \
        const float* Pb = pred + (size_t)nc * (W * H);                       \
        const float* Tb = targ + (size_t)nc * (W * H);                       \
        _Pragma("unroll")                                                    \
        for (int s = 0; s < 8; ++s) {                                        \
            const int gy = y0 - 8 + pr[s];                                   \
            const int gx = x0 + pc[s];                                       \
            const bool ok = ((unsigned)gy < H) && ((unsigned)gx < W);        \
            const float* bp = (wo[s] >= ARRB) ? Tb : Pb;                     \
            f32x4 v = zero4;                                                 \
            if (ok) v = *(const f32x4*)(bp + (size_t)gy * W + gx);           \
            pre[s] = v;                                                      \
        }                                                                    \
        __builtin_amdgcn_sched_barrier(0); /* pin load issue here */         \
    }

#define WRITES(BUF)                                                          \
    {                                                                        \
        _Pragma("unroll")                                                    \
        for (int s = 0; s < 8; ++s) {                                        \
            if (wo[s] >= 0) {                                                \
                half4 hv;                                                    \
                hv[0] = (_Float16)pre[s][0]; hv[1] = (_Float16)pre[s][1];    \
                hv[2] = (_Float16)pre[s][2]; hv[3] = (_Float16)pre[s][3];    \
                *(half4*)((char*)(BUF) + wo[s]) = hv;                        \
            }                                                                \
        }                                                                    \
    }

// H-pass: 10 tasks (rt 0..4 x ct 0..1) over 4 waves. A row m=lo = staged row
// 16rt+lo; k = staged col 16ct+k. Masked store keeps TP idx 77..79 zero.
#define HPASS(BUF)                                                           \
    {                                                                        \
        _Pragma("unroll")                                                    \
        for (int it = 0; it < 3; ++it) {                                     \
            const int t = wv + it * 4;                                       \
            if (t < 10) {                                                    \
                const int rt = t >> 1, ct = t & 1;                           \
                const int hb = (rt * 16 + lo) * SSTR + ct * 16 + hi * 8;     \
                const half4 pA = *(const half4*)(BUF + hb);                  \
                const half4 pB = *(const half4*)(BUF + hb + 4);              \
                const half4 tA = *(const half4*)(BUF + AH + hb);             \
                const half4 tB = *(const half4*)(BUF + AH + hb + 4);         \
                const half8 pa = __builtin_shufflevector(pA, pB, 0,1,2,3,4,5,6,7); \
                const half8 ta = __builtin_shufflevector(tA, tB, 0,1,2,3,4,5,6,7); \
                const half8 qa = pa * pa + ta * ta;                          \
                const half8 xa = pa * ta;                                    \
                const f32x4 d0 = MFMA(pa, Bw);                               \
                const f32x4 d1 = MFMA(ta, Bw);                               \
                const f32x4 d2 = MFMA(qa, Bw);                               \
                const f32x4 d3 = MFMA(xa, Bw);                               \
                const int tb = (ct * 16 + lo) * TPSTR + rt * 16 + hi * 4;    \
                if (rt == 4 && hi == 3) {      /* only idx 76 is real */     \
                    TP[0 * TPL + tb] = (_Float16)d0[0];                      \
                    TP[1 * TPL + tb] = (_Float16)d1[0];                      \
                    TP[2 * TPL + tb] = (_Float16)d2[0];                      \
                    TP[3 * TPL + tb] = (_Float16)d3[0];                      \
                } else {                                                     \
                    half4 h0, h1, h2, h3;                                    \
                    _Pragma("unroll")                                        \
                    for (int r = 0; r < 4; ++r) {                            \
                        h0[r] = (_Float16)d0[r]; h1[r] = (_Float16)d1[r];    \
                        h2[r] = (_Float16)d2[r]; h3[r] = (_Float16)d3[r];    \
                    }                                                        \
                    *(half4*)&TP[0 * TPL + tb] = h0;                         \
                    *(half4*)&TP[1 * TPL + tb] = h1;                         \
                    *(half4*)&TP[2 * TPL + tb] = h2;                         \
                    *(half4*)&TP[3 * TPL + tb] = h3;                         \
                }                                                            \
            }                                                                \
        }                                                                    \
    }

// V-pass: 8 tasks (rtv 0..3 x ct 0..1), 2 per wave; 16B-aligned b128 reads.
#define VPASS()                                                              \
    {                                                                        \
        _Pragma("unroll")                                                    \
        for (int iv = 0; iv < 2; ++iv) {                                     \
            const int v = wv + iv * 4;                                       \
            const int rtv = v >> 1, ct = v & 1;                              \
            const int ah = (ct * 16 + lo) * TPSTR + rtv * 16 + hi * 8;       \
            const half8 a0 = *(const half8*)&TP[0 * TPL + ah];               \
            const half8 a1 = *(const half8*)&TP[1 * TPL + ah];               \
            const half8 a2 = *(const half8*)&TP[2 * TPL + ah];               \
            const half8 a3 = *(const half8*)&TP[3 * TPL + ah];               \
            const f32x4 m1 = MFMA(a0, Bw);                                   \
            const f32x4 m2 = MFMA(a1, Bw);                                   \
            const f32x4 qq = MFMA(a2, Bw);                                   \
            const f32x4 pt = MFMA(a3, Bw);                                   \
            _Pragma("unroll")                                                \
            for (int r = 0; r < 4; ++r) {                                    \
                const float mu1 = m1[r], mu2 = m2[r];                        \
                const float ms  = fmaf(mu1, mu1, mu2 * mu2);                 \
                const float m12 = mu1 * mu2;                                 \
                const float s12 = pt[r] - m12;                               \
                const float ssm = qq[r] - ms;                                \
                const float num = fmaf(2.f, m12, C1) * fmaf(2.f, s12, C2);   \
                const float den = (ms + C1) * (ssm + C2);                    \
                sum += num * __builtin_amdgcn_rcpf(den);                     \
            }                                                                \
        }                                                                    \
    }

    // ---- Prologue: load+convert+write tile 0 into A. ----
    LOADREGS(t0);
    VMCNT0();
    WRITES(stageA);
    LGKM0(); BAR();

    // ---- Main loop: 2 tiles per iteration, static ping-pong (NT even). ----
    #pragma unroll 1
    for (int i = 0; i < NT; i += 2) {
        LOADREGS(t0 + i + 1);
        HPASS(stageA);
        LGKM0(); BAR();
        VPASS();
        VMCNT0();
        WRITES(stageB);
        LGKM0(); BAR();

        if (i + 2 < NT) LOADREGS(t0 + i + 2);
        HPASS(stageB);
        LGKM0(); BAR();
        VPASS();
        if (i + 2 < NT) {
            VMCNT0();
            WRITES(stageA);
        }
        LGKM0(); BAR();
    }

    // ---- Reduce: wave -> block -> one atomic per block (64 slots). ----
    #pragma unroll
    for (int off = 32; off > 0; off >>= 1) sum += __shfl_down(sum, off, 64);
    if (lane == 0) wsum[wv] = sum;
    __syncthreads();
    if (tid == 0)
        atomicAdd(&acc[bsw & (NACC - 1)], wsum[0] + wsum[1] + wsum[2] + wsum[3]);
#undef LOADREGS
#undef WRITES
#undef HPASS
#undef VPASS
}

__global__ void ssim_final(const float* __restrict__ acc, float* __restrict__ out) {
    float s = 0.f;
    #pragma unroll
    for (int i = 0; i < NACC; ++i) s += acc[i];
    out[0] = 0.1f * (1.0f - s / NPIX);
}

extern "C" void kernel_launch(void* const* d_in, const int* in_sizes, int n_in,
                              void* d_out, int out_size, void* d_ws, size_t ws_size,
                              hipStream_t stream) {
    const float* pred = (const float*)d_in[0];
    const float* targ = (const float*)d_in[1];
    const float* win  = (const float*)d_in[2];
    float* out = (float*)d_out;
    float* acc = (float*)d_ws;

    hipMemsetAsync(acc, 0, NACC * sizeof(float), stream);  // fresh accumulators
    ssim_main<<<768, 256, 0, stream>>>(pred, targ, win, acc);
    ssim_final<<<1, 1, 0, stream>>>(acc, out);
}